// Round 2
// baseline (76257.489 us; speedup 1.0000x reference)
//
#include <hip/hip_runtime.h>
#include <hip/hip_bf16.h>
#include <stdint.h>

// Dims
#define STEPS  200
#define KA     1792   // p(256) + ctx(512) + ah(1024)
#define KD     2560   // ah(1024) + ctx(512) + dh(1024)
#define NBLK   256

using bf16 = __bf16;
typedef __bf16 bf16x8 __attribute__((ext_vector_type(8)));
typedef float  f32x4  __attribute__((ext_vector_type(4)));

#define MFMA16(a,b,c) __builtin_amdgcn_mfma_f32_16x16x32_bf16((a),(b),(c),0,0,0)

__device__ __forceinline__ float sigf(float x){ return 1.f/(1.f+__expf(-x)); }
__device__ __forceinline__ float tanhf_(float x){
  float ax = fabsf(x);
  float e  = __expf(-2.f*ax);
  float t  = (1.f-e)/(1.f+e);
  return x < 0.f ? -t : t;
}

// ---------------- prologue conversion kernels ----------------
__global__ void cvt_kernel(const float* __restrict__ s, bf16* __restrict__ d, int n){
  int i = blockIdx.x*256 + threadIdx.x;
  if (i < n) d[i] = (bf16)s[i];
}
__global__ void cvt_pad_kernel(const float* __restrict__ s, bf16* __restrict__ d,
                               int rows, int cin, int cout){
  int i = blockIdx.x*256 + threadIdx.x;
  if (i >= rows*cout) return;
  int r = i / cout, c = i % cout;
  d[i] = (bf16)(c < cin ? s[(size_t)r*cin + c] : 0.f);
}
__global__ void cat_cvt_kernel(const float* __restrict__ s1, int c1,
                               const float* __restrict__ s2, int c2,
                               bf16* __restrict__ d, int rows){
  int C = c1 + c2;
  int i = blockIdx.x*256 + threadIdx.x;
  if (i >= rows*C) return;
  int r = i / C, c = i % C;
  float v = (c < c1) ? s1[(size_t)r*c1 + c] : s2[(size_t)r*c2 + (c - c1)];
  d[i] = (bf16)v;
}
__global__ void build_wmelcat(const float* __restrict__ Wmel, const float* __restrict__ Wstop,
                              bf16* __restrict__ d){
  int i = blockIdx.x*256 + threadIdx.x;
  if (i >= 176*1536) return;
  int r = i / 1536, c = i % 1536;
  float v = (r < 160) ? Wmel[(size_t)r*1536 + c] : (r == 160 ? Wstop[c] : 0.f);
  d[i] = (bf16)v;
}
__global__ void build_misc(const float* biha, const float* bhha, float* biasa,
                           const float* bihd, const float* bhhd, float* biasd,
                           const float* bmel, const float* bstop, float* bias176){
  int i = blockIdx.x*256 + threadIdx.x;
  if (i < 4096) biasa[i] = biha[i] + bhha[i];
  else if (i < 8192) { int j = i-4096; biasd[j] = bihd[j] + bhhd[j]; }
  else if (i < 8192+176) {
    int j = i - 8192;
    bias176[j] = (j < 160) ? bmel[j] : (j == 160 ? bstop[0] : 0.f);
  }
}
// dec_in (teacher forcing): row = s*64+b (200x64), 96 cols (80 real + 16 zero-pad)
__global__ void build_decin(const float* __restrict__ inp, bf16* __restrict__ d){
  int i = blockIdx.x*256 + threadIdx.x;
  if (i >= 12800*96) return;
  int row = i / 96, c = i % 96;
  int s = row >> 6, b = row & 63;
  float v = 0.f;
  if (c < 80 && s > 0) v = inp[((size_t)b*400 + (2*s - 1))*80 + c];
  d[i] = (bf16)v;
}

// ---------------- generic MFMA GEMM (prologue/epilogue batched use) ----------------
template<int ACT, int OBF>
__global__ __launch_bounds__(256)
void gemm_k(const bf16* __restrict__ A, const bf16* __restrict__ Bm,
            const float* __restrict__ bias, float* __restrict__ Cf,
            bf16* __restrict__ Cb, int M, int N, int K, int MT)
{
  int wid = blockIdx.x*4 + (threadIdx.x >> 6);
  if (wid >= MT*(N >> 4)) return;
  int wm = wid % MT, wn = wid / MT;
  int l = threadIdx.x & 63, lo = l & 15, hi = l >> 4;
  const bf16* Bp = Bm + (size_t)(wn*16 + lo)*K + hi*8;
  const bf16* Ap = A  + (size_t)(wm*64 + lo)*K + hi*8;
  f32x4 acc0 = {0,0,0,0}, acc1 = {0,0,0,0}, acc2 = {0,0,0,0}, acc3 = {0,0,0,0};
  for (int k = 0; k < K; k += 32){
    bf16x8 bb = *(const bf16x8*)(Bp + k);
    bf16x8 a0 = *(const bf16x8*)(Ap + k);
    bf16x8 a1 = *(const bf16x8*)(Ap + (size_t)16*K + k);
    bf16x8 a2 = *(const bf16x8*)(Ap + (size_t)32*K + k);
    bf16x8 a3 = *(const bf16x8*)(Ap + (size_t)48*K + k);
    acc0 = MFMA16(a0, bb, acc0);
    acc1 = MFMA16(a1, bb, acc1);
    acc2 = MFMA16(a2, bb, acc2);
    acc3 = MFMA16(a3, bb, acc3);
  }
  int n = wn*16 + lo;
  float bv = bias ? bias[n] : 0.f;
  int m0 = wm*64 + hi*4;
  #pragma unroll
  for (int mt = 0; mt < 4; ++mt){
    f32x4 av = (mt==0)?acc0:(mt==1)?acc1:(mt==2)?acc2:acc3;
    #pragma unroll
    for (int r = 0; r < 4; ++r){
      float v = av[r] + bv;
      if (ACT) v = fmaxf(v, 0.f);
      size_t idx = (size_t)(m0 + mt*16 + r)*N + n;
      if (OBF) Cb[idx] = (bf16)v; else Cf[idx] = v;
    }
  }
}

// ---------------- grid barrier (agent-scope, monotonic counter) --------------------
__device__ __forceinline__ void gridbar(unsigned* cnt, unsigned target){
  __syncthreads();
  if (threadIdx.x == 0){
    __threadfence();   // make prior global writes visible at agent scope
    __hip_atomic_fetch_add(cnt, 1u, __ATOMIC_RELEASE, __HIP_MEMORY_SCOPE_AGENT);
    while (__hip_atomic_load(cnt, __ATOMIC_ACQUIRE, __HIP_MEMORY_SCOPE_AGENT) < target)
      __builtin_amdgcn_s_sleep(1);
    __threadfence();   // acquire: invalidate caches before subsequent reads
  }
  __syncthreads();
}

// ---------------- THE persistent scan kernel ---------------------------------------
// grid = 256 blocks (1/CU, guaranteed co-resident), 256 threads.
// Phase A: blocks 0-127 -> Ga (N=4096,K=1792), blocks 128-255 -> Gd (N=4096,K=2560).
//   Per block: 2 output tiles (64x16), each computed by 2 waves (split-K/2) + LDS add.
// Phase B: blocks 0-63 own batch b: cell updates, conv, q, energies, softmax, ctx.
__global__ __launch_bounds__(256, 1)
void decoder_scan(const bf16* __restrict__ pall,
                  const bf16* __restrict__ Wa, const bf16* __restrict__ Wd,
                  const float* __restrict__ biasa, const float* __restrict__ biasd,
                  const bf16* __restrict__ Wqb, const float* __restrict__ Wconv,
                  const float* __restrict__ Wloc, const float* __restrict__ vvp,
                  const float* __restrict__ pm, const bf16* __restrict__ enc_bf,
                  bf16* __restrict__ xa, bf16* __restrict__ xd,
                  float* __restrict__ ga, float* __restrict__ gd,
                  float* __restrict__ ac, float* __restrict__ dc,
                  bf16* __restrict__ proj, float* __restrict__ out_attn,
                  unsigned* __restrict__ cnt)
{
  const int tid = threadIdx.x;
  const int l = tid & 63, lo = l & 15, hi = l >> 4;

  __shared__ float red[2][64][17];            // split-K reduce
  __shared__ float locb[200][32];             // conv features
  __shared__ float wlocT[32][128];            // Wloc transposed (persist)
  __shared__ float awl[256];                  // alignment (persists across steps)
  __shared__ float qp[256];
  __shared__ float qv[128];
  __shared__ float es[200];
  __shared__ float sred[4];
  __shared__ __align__(16) bf16 ahs[1024];

  // phase-A static assignment
  const bool isA  = blockIdx.x < 128;
  const int  tloc = tid >> 7;                 // tile within block (0/1)
  const int  kh   = (tid >> 6) & 1;           // k-half (0/1)
  const int  n0   = ((isA ? blockIdx.x : blockIdx.x - 128)*2 + tloc) * 16;
  const int  K    = isA ? KA : KD;
  const int  khalf= K >> 1;
  const bf16* Wg  = isA ? Wa : Wd;
  const bf16* X   = isA ? xa : xd;
  float*      G   = isA ? ga : gd;
  const bf16* Bp0 = Wg + (size_t)(n0 + lo)*K + kh*khalf + hi*8;
  const bf16* Ap0 = X  + (size_t)lo*K        + kh*khalf + hi*8;

  unsigned nb = 0;

  // pre-loop: p_0 into xa, zero alignment LDS, build wlocT (persists)
  if (blockIdx.x < 64){
    const int b = blockIdx.x;
    if (tid < 200) awl[tid] = 0.f;
    xa[(size_t)b*1792 + tid] = pall[(size_t)b*256 + tid];
    for (int it = tid; it < 4096; it += 256)
      wlocT[it >> 7][it & 127] = Wloc[(it & 127)*32 + (it >> 7)];
  }
  gridbar(cnt, ++nb * NBLK);

  for (int i = 0; i <= STEPS; ++i){
    // =========================== phase A: gate GEMMs ===========================
    const bool work = isA ? (i < STEPS) : (i > 0);
    f32x4 acc0={0,0,0,0}, acc1={0,0,0,0}, acc2={0,0,0,0}, acc3={0,0,0,0};
    if (work){
      const bf16* Bp = Bp0;
      const bf16* Ap = Ap0;
      #pragma unroll 2
      for (int k = 0; k < khalf; k += 32){
        bf16x8 bb = *(const bf16x8*)(Bp + k);
        bf16x8 a0 = *(const bf16x8*)(Ap + k);
        bf16x8 a1 = *(const bf16x8*)(Ap + (size_t)16*K + k);
        bf16x8 a2 = *(const bf16x8*)(Ap + (size_t)32*K + k);
        bf16x8 a3 = *(const bf16x8*)(Ap + (size_t)48*K + k);
        acc0 = MFMA16(a0, bb, acc0);
        acc1 = MFMA16(a1, bb, acc1);
        acc2 = MFMA16(a2, bb, acc2);
        acc3 = MFMA16(a3, bb, acc3);
      }
      if (kh == 0){
        #pragma unroll
        for (int r = 0; r < 4; ++r){
          red[tloc][      hi*4+r][lo] = acc0[r];
          red[tloc][16 +  hi*4+r][lo] = acc1[r];
          red[tloc][32 +  hi*4+r][lo] = acc2[r];
          red[tloc][48 +  hi*4+r][lo] = acc3[r];
        }
      }
    }
    __syncthreads();
    if (work && kh == 1){
      #pragma unroll
      for (int mt = 0; mt < 4; ++mt){
        f32x4 av = (mt==0)?acc0:(mt==1)?acc1:(mt==2)?acc2:acc3;
        #pragma unroll
        for (int r = 0; r < 4; ++r){
          int m = mt*16 + hi*4 + r;
          G[(size_t)m*4096 + n0 + lo] = red[tloc][m][lo] + av[r];
        }
      }
    }
    gridbar(cnt, ++nb * NBLK);

    // =========================== phase B: state + attention ====================
    if (blockIdx.x < 64){
      const int b = blockIdx.x;
      if (i > 0){
        // dec LSTM cell update (step i-1)
        for (int u = tid; u < 1024; u += 256){
          float iv = gd[b*4096 + u]        + biasd[u];
          float fv = gd[b*4096 + 1024 + u] + biasd[1024+u];
          float gv = gd[b*4096 + 2048 + u] + biasd[2048+u];
          float ov = gd[b*4096 + 3072 + u] + biasd[3072+u];
          float c  = sigf(fv)*dc[b*1024+u] + sigf(iv)*tanhf_(gv);
          float h  = sigf(ov)*tanhf_(c);
          dc[b*1024+u] = c;
          bf16 hb = (bf16)h;
          xd[(size_t)b*2560 + 1536 + u] = hb;
          proj[((size_t)(i-1)*64 + b)*1536 + u] = hb;
        }
      }
      if (i < STEPS){
        // attn LSTM cell update (step i)
        for (int u = tid; u < 1024; u += 256){
          float iv = ga[b*4096 + u]        + biasa[u];
          float fv = ga[b*4096 + 1024 + u] + biasa[1024+u];
          float gv = ga[b*4096 + 2048 + u] + biasa[2048+u];
          float ov = ga[b*4096 + 3072 + u] + biasa[3072+u];
          float c  = sigf(fv)*ac[b*1024+u] + sigf(iv)*tanhf_(gv);
          float h  = sigf(ov)*tanhf_(c);
          ac[b*1024+u] = c;
          bf16 hb = (bf16)h;
          ahs[u] = hb;
          xa[(size_t)b*1792 + 768 + u] = hb;
          xd[(size_t)b*2560 + u]       = hb;
        }
        // teacher-forced prenet input for step i+1
        if (i < STEPS-1)
          xa[(size_t)b*1792 + tid] = pall[((size_t)(i+1)*64 + b)*256 + tid];
        __syncthreads();  // ahs ready
        // conv1d(31) of previous alignment (awl persists in LDS)
        for (int it = tid; it < 6400; it += 256){
          int f = it & 31, tl = it >> 5;
          float s = 0.f;
          #pragma unroll
          for (int j = 0; j < 31; ++j){
            int tt = tl + j - 15;
            if ((unsigned)tt < 200u) s += awl[tt]*Wconv[f*31+j];
          }
          locb[tl][f] = s;
        }
        // q = ah @ Wq^T
        {
          int a = tid & 127, hf = tid >> 7;
          const bf16* wr = Wqb + (size_t)a*1024 + hf*512;
          float s = 0.f;
          for (int k2 = 0; k2 < 512; k2 += 8){
            bf16x8 x = *(const bf16x8*)(&ahs[hf*512 + k2]);
            bf16x8 y = *(const bf16x8*)(wr + k2);
            #pragma unroll
            for (int e = 0; e < 8; ++e) s += (float)x[e]*(float)y[e];
          }
          qp[tid] = s;
        }
        __syncthreads();
        if (tid < 128) qv[tid] = qp[tid] + qp[tid+128];
        __syncthreads();
        // energies
        {
          const int wv = tid >> 6;
          for (int tl = wv; tl < 200; tl += 4){
            const float* pmrow = pm + ((size_t)b*200 + tl)*128;
            float s = 0.f;
            #pragma unroll
            for (int half = 0; half < 2; ++half){
              int a = l + half*64;
              float x = qv[a] + pmrow[a];
              #pragma unroll
              for (int f = 0; f < 32; ++f) x += locb[tl][f]*wlocT[f][a];
              s += vvp[a]*tanhf_(x);
            }
            #pragma unroll
            for (int o = 32; o; o >>= 1) s += __shfl_xor(s, o);
            if (l == 0) es[tl] = s;
          }
        }
        __syncthreads();
        // softmax over 200 (result -> awl, out_attn)
        {
          float e0 = (tid < 200) ? es[tid] : -3.0e38f;
          float m = e0;
          #pragma unroll
          for (int o = 32; o; o >>= 1) m = fmaxf(m, __shfl_xor(m, o));
          if (l == 0) sred[tid>>6] = m;
          __syncthreads();
          m = fmaxf(fmaxf(sred[0],sred[1]), fmaxf(sred[2],sred[3]));
          float p = (tid < 200) ? __expf(e0 - m) : 0.f;
          float ss = p;
          #pragma unroll
          for (int o = 32; o; o >>= 1) ss += __shfl_xor(ss, o);
          __syncthreads();
          if (l == 0) sred[tid>>6] = ss;
          __syncthreads();
          ss = sred[0]+sred[1]+sred[2]+sred[3];
          float aval = p / ss;
          if (tid < 200){
            awl[tid] = aval;
            out_attn[((size_t)b*200 + i)*200 + tid] = aval;
          }
        }
        __syncthreads();
        // context = align @ enc
        #pragma unroll
        for (int rep = 0; rep < 2; ++rep){
          int d = tid + rep*256;
          const bf16* ep = enc_bf + (size_t)b*102400 + d;
          float s = 0.f;
          #pragma unroll 4
          for (int t = 0; t < 200; ++t) s += awl[t]*(float)ep[(size_t)t*512];
          bf16 cb = (bf16)s;
          xa[(size_t)b*1792 + 256 + d]  = cb;
          xd[(size_t)b*2560 + 1024 + d] = cb;
          proj[((size_t)i*64 + b)*1536 + 1024 + d] = cb;
        }
      }
    }
    gridbar(cnt, ++nb * NBLK);
  }
}

// ---------------- epilogue scatter -------------------------------------------------
__global__ void scatter_out(const float* __restrict__ mt_, float* __restrict__ out){
  int i = blockIdx.x*256 + threadIdx.x;
  const int NMEL = 12800*160;
  if (i < NMEL){
    int sb = i / 160, j = i % 160;
    int s = sb >> 6, b = sb & 63;
    int r = j / 80, mm = j % 80;
    out[((size_t)b*400 + 2*s + r)*80 + mm] = mt_[(size_t)sb*176 + j];
  } else if (i < NMEL + 12800){
    int sb = i - NMEL;
    int s = sb >> 6, b = sb & 63;
    float st = sigf(mt_[(size_t)sb*176 + 160]);
    float* so = out + 2048000;
    so[(size_t)b*400 + 2*s]     = st;
    so[(size_t)b*400 + 2*s + 1] = st;
  }
}

// ==================================================================================
extern "C" void kernel_launch(void* const* d_in, const int* in_sizes, int n_in,
                              void* d_out, int out_size, void* d_ws, size_t ws_size,
                              hipStream_t stream)
{
  const float* enc   = (const float*)d_in[0];
  const float* inp   = (const float*)d_in[1];
  const float* Wpre1 = (const float*)d_in[2];
  const float* bpre1 = (const float*)d_in[3];
  const float* Wpre2 = (const float*)d_in[4];
  const float* bpre2 = (const float*)d_in[5];
  const float* Wmem  = (const float*)d_in[6];
  const float* Wiha  = (const float*)d_in[7];
  const float* Whha  = (const float*)d_in[8];
  const float* biha  = (const float*)d_in[9];
  const float* bhha  = (const float*)d_in[10];
  const float* Wq    = (const float*)d_in[11];
  const float* Wconv = (const float*)d_in[12];
  const float* Wloc  = (const float*)d_in[13];
  const float* vv    = (const float*)d_in[14];
  const float* Wihd  = (const float*)d_in[15];
  const float* Whhd  = (const float*)d_in[16];
  const float* bihd  = (const float*)d_in[17];
  const float* bhhd  = (const float*)d_in[18];
  const float* Wmel  = (const float*)d_in[19];
  const float* bmel  = (const float*)d_in[20];
  const float* Wstop = (const float*)d_in[21];
  const float* bstop = (const float*)d_in[22];
  float* out = (float*)d_out;

  char* pp = (char*)d_ws;
  auto carve = [&](size_t bytes)->char*{
    char* r = (char*)(((uintptr_t)pp + 255) & ~(uintptr_t)255);
    pp = r + bytes;
    return r;
  };
  bf16*  enc_bf  = (bf16*) carve((size_t)64*200*512*2);
  float* pm      = (float*)carve((size_t)64*200*128*4);
  bf16*  decin   = (bf16*) carve((size_t)12800*96*2);
  bf16*  h1      = (bf16*) carve((size_t)12800*256*2);
  bf16*  pall    = (bf16*) carve((size_t)12800*256*2);
  bf16*  Wp1b    = (bf16*) carve((size_t)256*96*2);
  bf16*  Wp2b    = (bf16*) carve((size_t)256*256*2);
  bf16*  Wmemb   = (bf16*) carve((size_t)128*512*2);
  bf16*  Wqb     = (bf16*) carve((size_t)128*1024*2);
  bf16*  Wca     = (bf16*) carve((size_t)4096*KA*2);
  bf16*  Wcd     = (bf16*) carve((size_t)4096*KD*2);
  bf16*  Wmc     = (bf16*) carve((size_t)176*1536*2);
  float* biasa   = (float*)carve(4096*4);
  float* biasd   = (float*)carve(4096*4);
  float* bias176 = (float*)carve(176*4);
  bf16*  proj    = (bf16*) carve((size_t)12800*1536*2);
  float* meltmp  = (float*)carve((size_t)12800*176*4);
  float* ga      = (float*)carve((size_t)64*4096*4);
  float* gd      = (float*)carve((size_t)64*4096*4);
  // zeroed-every-launch state block (contiguous)
  bf16*  xa  = (bf16*) carve((size_t)64*1792*2);
  bf16*  xd  = (bf16*) carve((size_t)64*2560*2);
  float* ac  = (float*)carve((size_t)64*1024*4);
  float* dc  = (float*)carve((size_t)64*1024*4);
  unsigned* cnt = (unsigned*)carve(256);
  size_t zbytes = (size_t)((char*)cnt + 256 - (char*)xa);
  hipMemsetAsync(xa, 0, zbytes, stream);

  // ---- prologue: conversions / packing ----
  cvt_kernel<<<(6553600+255)/256,256,0,stream>>>(enc,   enc_bf, 6553600);
  cvt_kernel<<<(131072+255)/256, 256,0,stream>>>(Wq,    Wqb,    131072);
  cvt_kernel<<<(65536+255)/256,  256,0,stream>>>(Wmem,  Wmemb,  65536);
  cvt_kernel<<<(65536+255)/256,  256,0,stream>>>(Wpre2, Wp2b,   65536);
  cvt_pad_kernel<<<(256*96+255)/256,256,0,stream>>>(Wpre1, Wp1b, 256, 80, 96);
  cat_cvt_kernel<<<(4096*KA+255)/256,256,0,stream>>>(Wiha, 768,  Whha, 1024, Wca, 4096);
  cat_cvt_kernel<<<(4096*KD+255)/256,256,0,stream>>>(Wihd, 1536, Whhd, 1024, Wcd, 4096);
  build_wmelcat<<<(176*1536+255)/256,256,0,stream>>>(Wmel, Wstop, Wmc);
  build_misc<<<(8368+255)/256,256,0,stream>>>(biha,bhha,biasa, bihd,bhhd,biasd, bmel,bstop,bias176);
  build_decin<<<(12800*96+255)/256,256,0,stream>>>(inp, decin);

  // ---- prologue: batched GEMMs ----
  gemm_k<1,1><<<800,256,0,stream>>>(decin, Wp1b, bpre1, nullptr, h1, 12800,256,96, 200);
  gemm_k<1,1><<<800,256,0,stream>>>(h1, Wp2b, bpre2, nullptr, pall, 12800,256,256, 200);
  gemm_k<0,0><<<400,256,0,stream>>>(enc_bf, Wmemb, nullptr, pm, nullptr, 12800,128,512, 200);

  // ---- the whole 200-step scan as ONE persistent kernel ----
  float* out_attn = out + 2073600;
  decoder_scan<<<NBLK,256,0,stream>>>(pall, Wca, Wcd, biasa, biasd,
                                      Wqb, Wconv, Wloc, vv, pm, enc_bf,
                                      xa, xd, ga, gd, ac, dc,
                                      proj, out_attn, cnt);

  // ---- epilogue: mel/stop projection + scatter ----
  gemm_k<0,0><<<550,256,0,stream>>>(proj, Wmc, bias176, meltmp, nullptr, 12800,176,1536, 200);
  scatter_out<<<(12800*160+12800+255)/256,256,0,stream>>>(meltmp, out);
}

// Round 3
// 31337.799 us; speedup vs baseline: 2.4334x; 2.4334x over previous
//
#include <hip/hip_runtime.h>
#include <hip/hip_bf16.h>
#include <stdint.h>

// Dims
#define STEPS  200
#define KA     1792   // p(256) + ctx(512) + ah(1024)
#define KD     2560   // ah(1024) + ctx(512) + dh(1024)
#define NBLK   256

using bf16 = __bf16;
typedef __bf16 bf16x8 __attribute__((ext_vector_type(8)));
typedef float  f32x4  __attribute__((ext_vector_type(4)));
typedef unsigned int       u32;
typedef unsigned long long u64;

union U8v { u64 q[2]; bf16x8 v; };
union U2f { u64 q; float f[2]; };
union U2h { u32 u; bf16 h[2]; };
union U4h { u32 u[2]; bf16 h[4]; };

#define MFMA16(a,b,c) __builtin_amdgcn_mfma_f32_16x16x32_bf16((a),(b),(c),0,0,0)

__device__ __forceinline__ float sigf(float x){ return 1.f/(1.f+__expf(-x)); }
__device__ __forceinline__ float tanhf_(float x){
  float ax = fabsf(x);
  float e  = __expf(-2.f*ax);
  float t  = (1.f-e)/(1.f+e);
  return x < 0.f ? -t : t;
}

// coherent (agent-scope, L2-bypass) accessors — no cache maintenance
__device__ __forceinline__ u64 ldq(const u64* p){
  return __hip_atomic_load((u64*)p, __ATOMIC_RELAXED, __HIP_MEMORY_SCOPE_AGENT);
}
__device__ __forceinline__ float ldf(const float* p){
  return __hip_atomic_load((float*)p, __ATOMIC_RELAXED, __HIP_MEMORY_SCOPE_AGENT);
}
__device__ __forceinline__ void stf(float* p, float v){
  __hip_atomic_store(p, v, __ATOMIC_RELAXED, __HIP_MEMORY_SCOPE_AGENT);
}
__device__ __forceinline__ void stu(u32* p, u32 v){
  __hip_atomic_store(p, v, __ATOMIC_RELAXED, __HIP_MEMORY_SCOPE_AGENT);
}

// ---------------- prologue conversion kernels ----------------
__global__ void cvt_kernel(const float* __restrict__ s, bf16* __restrict__ d, int n){
  int i = blockIdx.x*256 + threadIdx.x;
  if (i < n) d[i] = (bf16)s[i];
}
__global__ void cvt_pad_kernel(const float* __restrict__ s, bf16* __restrict__ d,
                               int rows, int cin, int cout){
  int i = blockIdx.x*256 + threadIdx.x;
  if (i >= rows*cout) return;
  int r = i / cout, c = i % cout;
  d[i] = (bf16)(c < cin ? s[(size_t)r*cin + c] : 0.f);
}
__global__ void cat_cvt_kernel(const float* __restrict__ s1, int c1,
                               const float* __restrict__ s2, int c2,
                               bf16* __restrict__ d, int rows){
  int C = c1 + c2;
  int i = blockIdx.x*256 + threadIdx.x;
  if (i >= rows*C) return;
  int r = i / C, c = i % C;
  float v = (c < c1) ? s1[(size_t)r*c1 + c] : s2[(size_t)r*c2 + (c - c1)];
  d[i] = (bf16)v;
}
__global__ void build_wmelcat(const float* __restrict__ Wmel, const float* __restrict__ Wstop,
                              bf16* __restrict__ d){
  int i = blockIdx.x*256 + threadIdx.x;
  if (i >= 176*1536) return;
  int r = i / 1536, c = i % 1536;
  float v = (r < 160) ? Wmel[(size_t)r*1536 + c] : (r == 160 ? Wstop[c] : 0.f);
  d[i] = (bf16)v;
}
__global__ void build_misc(const float* biha, const float* bhha, float* biasa,
                           const float* bihd, const float* bhhd, float* biasd,
                           const float* bmel, const float* bstop, float* bias176){
  int i = blockIdx.x*256 + threadIdx.x;
  if (i < 4096) biasa[i] = biha[i] + bhha[i];
  else if (i < 8192) { int j = i-4096; biasd[j] = bihd[j] + bhhd[j]; }
  else if (i < 8192+176) {
    int j = i - 8192;
    bias176[j] = (j < 160) ? bmel[j] : (j == 160 ? bstop[0] : 0.f);
  }
}
__global__ void build_decin(const float* __restrict__ inp, bf16* __restrict__ d){
  int i = blockIdx.x*256 + threadIdx.x;
  if (i >= 12800*96) return;
  int row = i / 96, c = i % 96;
  int s = row >> 6, b = row & 63;
  float v = 0.f;
  if (c < 80 && s > 0) v = inp[((size_t)b*400 + (2*s - 1))*80 + c];
  d[i] = (bf16)v;
}

// ---------------- generic MFMA GEMM (prologue/epilogue batched use) ----------------
template<int ACT, int OBF>
__global__ __launch_bounds__(256)
void gemm_k(const bf16* __restrict__ A, const bf16* __restrict__ Bm,
            const float* __restrict__ bias, float* __restrict__ Cf,
            bf16* __restrict__ Cb, int M, int N, int K, int MT)
{
  int wid = blockIdx.x*4 + (threadIdx.x >> 6);
  if (wid >= MT*(N >> 4)) return;
  int wm = wid % MT, wn = wid / MT;
  int l = threadIdx.x & 63, lo = l & 15, hi = l >> 4;
  const bf16* Bp = Bm + (size_t)(wn*16 + lo)*K + hi*8;
  const bf16* Ap = A  + (size_t)(wm*64 + lo)*K + hi*8;
  f32x4 acc0 = {0,0,0,0}, acc1 = {0,0,0,0}, acc2 = {0,0,0,0}, acc3 = {0,0,0,0};
  for (int k = 0; k < K; k += 32){
    bf16x8 bb = *(const bf16x8*)(Bp + k);
    bf16x8 a0 = *(const bf16x8*)(Ap + k);
    bf16x8 a1 = *(const bf16x8*)(Ap + (size_t)16*K + k);
    bf16x8 a2 = *(const bf16x8*)(Ap + (size_t)32*K + k);
    bf16x8 a3 = *(const bf16x8*)(Ap + (size_t)48*K + k);
    acc0 = MFMA16(a0, bb, acc0);
    acc1 = MFMA16(a1, bb, acc1);
    acc2 = MFMA16(a2, bb, acc2);
    acc3 = MFMA16(a3, bb, acc3);
  }
  int n = wn*16 + lo;
  float bv = bias ? bias[n] : 0.f;
  int m0 = wm*64 + hi*4;
  #pragma unroll
  for (int mt = 0; mt < 4; ++mt){
    f32x4 av = (mt==0)?acc0:(mt==1)?acc1:(mt==2)?acc2:acc3;
    #pragma unroll
    for (int r = 0; r < 4; ++r){
      float v = av[r] + bv;
      if (ACT) v = fmaxf(v, 0.f);
      size_t idx = (size_t)(m0 + mt*16 + r)*N + n;
      if (OBF) Cb[idx] = (bf16)v; else Cf[idx] = v;
    }
  }
}

// ---------------- grid barrier: NO cache maintenance ------------------------------
// __syncthreads drains each wave's vmcnt (stores ack'd at LLC for sc1 ops);
// flag add/poll are relaxed agent atomics (sc1) so no L2 invalidation happens.
__device__ __forceinline__ void gridbar(unsigned* cnt, unsigned target){
  __syncthreads();
  if (threadIdx.x == 0){
    asm volatile("s_waitcnt vmcnt(0)" ::: "memory");
    __hip_atomic_fetch_add(cnt, 1u, __ATOMIC_RELAXED, __HIP_MEMORY_SCOPE_AGENT);
    while (__hip_atomic_load(cnt, __ATOMIC_RELAXED, __HIP_MEMORY_SCOPE_AGENT) < target)
      __builtin_amdgcn_s_sleep(4);
    asm volatile("" ::: "memory");
  }
  __syncthreads();
}

// ---------------- THE persistent scan kernel ---------------------------------------
// 256 blocks x 256 thr (1 block/CU). Phase A: blocks 0-127 -> ga tile (64x32 of
// N=4096, K=1792), blocks 128-255 -> gd tile (K=2560); 4 waves split K 4-ways,
// LDS reduce. Comm buffers (xa,xd,ga,gd,cnt) accessed ONLY via sc1 atomics.
// Weights/pm/enc/pall: normal cached loads, L2-resident across steps.
__global__ __launch_bounds__(256, 1)
void decoder_scan(const bf16* __restrict__ pall,
                  const bf16* __restrict__ Wa, const bf16* __restrict__ Wd,
                  const float* __restrict__ biasa, const float* __restrict__ biasd,
                  const bf16* __restrict__ Wqb, const float* __restrict__ Wconv,
                  const float* __restrict__ Wloc, const float* __restrict__ vvp,
                  const float* __restrict__ pm, const bf16* __restrict__ enc_bf,
                  bf16* __restrict__ xa, bf16* __restrict__ xd,
                  float* __restrict__ ga, float* __restrict__ gd,
                  float* __restrict__ ac, float* __restrict__ dc,
                  bf16* __restrict__ proj, float* __restrict__ out_attn,
                  unsigned* __restrict__ cnt)
{
  const int tid = threadIdx.x;
  const int l = tid & 63, lo = l & 15, hi = l >> 4;
  const int wv = tid >> 6;                    // wave id = k-quarter

  __shared__ float red[4][64][33];            // split-K partials (+1 pad)
  __shared__ float locb[200][32];
  __shared__ float wlocT[32][128];
  __shared__ float awl[256];
  __shared__ float qp[256];
  __shared__ float qv[128];
  __shared__ float es[200];
  __shared__ float sred[4];
  __shared__ __align__(16) bf16 ahs[1024];

  // phase-A static assignment: one 64x32 output tile per block
  const bool isA  = blockIdx.x < 128;
  const int  bq   = isA ? blockIdx.x : blockIdx.x - 128;
  const int  n0   = bq * 32;
  const int  K    = isA ? KA : KD;
  const int  kq   = K >> 2;
  const bf16* Wg  = isA ? Wa : Wd;
  const bf16* X   = isA ? xa : xd;
  float*      G   = isA ? ga : gd;
  const bf16* BpA = Wg + (size_t)(n0 + lo)*K + wv*kq + hi*8;
  const bf16* BpB = BpA + (size_t)16*K;
  const u64*  Ax  = (const u64*)X;
  const size_t aoff = ((size_t)lo*K + wv*kq + hi*8) >> 2;   // u64 units
  const size_t mstr = ((size_t)16*K) >> 2;

  unsigned nb = 0;

  // pre-loop init
  if (blockIdx.x < 64){
    const int b = blockIdx.x;
    if (tid < 200) awl[tid] = 0.f;
    if (tid < 128){
      u32 v = ((const u32*)(pall + (size_t)b*256))[tid];
      stu((u32*)(xa + (size_t)b*1792) + tid, v);
    }
    for (int it = tid; it < 4096; it += 256)
      wlocT[it >> 7][it & 127] = Wloc[(it & 127)*32 + (it >> 7)];
  }
  gridbar(cnt, ++nb * NBLK);

  for (int i = 0; i <= STEPS; ++i){
    // =========================== phase A: gate GEMM tile =======================
    const bool work = isA ? (i < STEPS) : (i > 0);
    if (work){
      f32x4 c00={0,0,0,0},c01={0,0,0,0},c02={0,0,0,0},c03={0,0,0,0};
      f32x4 c10={0,0,0,0},c11={0,0,0,0},c12={0,0,0,0},c13={0,0,0,0};
      #pragma unroll 2
      for (int k = 0; k < kq; k += 32){
        bf16x8 b0 = *(const bf16x8*)(BpA + k);
        bf16x8 b1 = *(const bf16x8*)(BpB + k);
        const u64* ap = Ax + aoff + (k >> 2);
        U8v a0, a1, a2, a3;
        a0.q[0]=ldq(ap);            a0.q[1]=ldq(ap+1);
        a1.q[0]=ldq(ap+mstr);       a1.q[1]=ldq(ap+mstr+1);
        a2.q[0]=ldq(ap+2*mstr);     a2.q[1]=ldq(ap+2*mstr+1);
        a3.q[0]=ldq(ap+3*mstr);     a3.q[1]=ldq(ap+3*mstr+1);
        c00=MFMA16(a0.v,b0,c00); c10=MFMA16(a0.v,b1,c10);
        c01=MFMA16(a1.v,b0,c01); c11=MFMA16(a1.v,b1,c11);
        c02=MFMA16(a2.v,b0,c02); c12=MFMA16(a2.v,b1,c12);
        c03=MFMA16(a3.v,b0,c03); c13=MFMA16(a3.v,b1,c13);
      }
      #define STACC(m, cA, cB) \
        _Pragma("unroll") \
        for (int r = 0; r < 4; ++r){ \
          red[wv][(m)*16 + hi*4 + r][lo]      = cA[r]; \
          red[wv][(m)*16 + hi*4 + r][16 + lo] = cB[r]; \
        }
      STACC(0, c00, c10) STACC(1, c01, c11) STACC(2, c02, c12) STACC(3, c03, c13)
      #undef STACC
    }
    __syncthreads();
    if (work){
      #pragma unroll
      for (int j = 0; j < 8; ++j){
        int idx = tid + j*256;
        int row = idx >> 5, col = idx & 31;
        float s = red[0][row][col] + red[1][row][col]
                + red[2][row][col] + red[3][row][col];
        stf(&G[(size_t)row*4096 + n0 + col], s);
      }
    }
    gridbar(cnt, ++nb * NBLK);

    // =========================== phase B: state + attention ====================
    if (blockIdx.x < 64){
      const int b = blockIdx.x;
      const int u0 = tid*4;
      if (i > 0){
        // dec LSTM cell update (step i-1)
        const u64* gp = (const u64*)(gd + (size_t)b*4096);
        float gg[16];
        #pragma unroll
        for (int g = 0; g < 4; ++g){
          U2f x0, x1;
          x0.q = ldq(gp + ((g*1024 + u0) >> 1));
          x1.q = ldq(gp + ((g*1024 + u0) >> 1) + 1);
          gg[g*4+0]=x0.f[0]; gg[g*4+1]=x0.f[1]; gg[g*4+2]=x1.f[0]; gg[g*4+3]=x1.f[1];
        }
        U4h hp;
        #pragma unroll
        for (int j = 0; j < 4; ++j){
          int u = u0 + j;
          float iv=gg[j]+biasd[u], fv=gg[4+j]+biasd[1024+u];
          float gv=gg[8+j]+biasd[2048+u], ov=gg[12+j]+biasd[3072+u];
          float c = sigf(fv)*dc[b*1024+u] + sigf(iv)*tanhf_(gv);
          float h = sigf(ov)*tanhf_(c);
          dc[b*1024+u] = c;
          bf16 hb = (bf16)h;
          hp.h[j] = hb;
          proj[((size_t)(i-1)*64 + b)*1536 + u] = hb;
        }
        u32* xp = (u32*)(xd + (size_t)b*2560 + 1536 + u0);
        stu(xp, hp.u[0]); stu(xp+1, hp.u[1]);
      }
      if (i < STEPS){
        // attn LSTM cell update (step i)
        {
          const u64* gp = (const u64*)(ga + (size_t)b*4096);
          float gg[16];
          #pragma unroll
          for (int g = 0; g < 4; ++g){
            U2f x0, x1;
            x0.q = ldq(gp + ((g*1024 + u0) >> 1));
            x1.q = ldq(gp + ((g*1024 + u0) >> 1) + 1);
            gg[g*4+0]=x0.f[0]; gg[g*4+1]=x0.f[1]; gg[g*4+2]=x1.f[0]; gg[g*4+3]=x1.f[1];
          }
          U4h hp;
          #pragma unroll
          for (int j = 0; j < 4; ++j){
            int u = u0 + j;
            float iv=gg[j]+biasa[u], fv=gg[4+j]+biasa[1024+u];
            float gv=gg[8+j]+biasa[2048+u], ov=gg[12+j]+biasa[3072+u];
            float c = sigf(fv)*ac[b*1024+u] + sigf(iv)*tanhf_(gv);
            float h = sigf(ov)*tanhf_(c);
            ac[b*1024+u] = c;
            bf16 hb = (bf16)h;
            hp.h[j] = hb;
            ahs[u] = hb;
          }
          u32* xpa = (u32*)(xa + (size_t)b*1792 + 768 + u0);
          stu(xpa, hp.u[0]); stu(xpa+1, hp.u[1]);
          u32* xpd = (u32*)(xd + (size_t)b*2560 + u0);
          stu(xpd, hp.u[0]); stu(xpd+1, hp.u[1]);
        }
        // teacher-forced prenet input for step i+1
        if (i < STEPS-1 && tid < 128){
          u32 v = ((const u32*)(pall + ((size_t)(i+1)*64 + b)*256))[tid];
          stu((u32*)(xa + (size_t)b*1792) + tid, v);
        }
        __syncthreads();  // ahs ready
        // conv1d(31) of previous alignment
        for (int it = tid; it < 6400; it += 256){
          int f = it & 31, tl = it >> 5;
          float s = 0.f;
          #pragma unroll
          for (int j = 0; j < 31; ++j){
            int tt = tl + j - 15;
            if ((unsigned)tt < 200u) s += awl[tt]*Wconv[f*31+j];
          }
          locb[tl][f] = s;
        }
        // q = ah @ Wq^T
        {
          int a = tid & 127, hf = tid >> 7;
          const bf16* wr = Wqb + (size_t)a*1024 + hf*512;
          float s = 0.f;
          for (int k2 = 0; k2 < 512; k2 += 8){
            bf16x8 x = *(const bf16x8*)(&ahs[hf*512 + k2]);
            bf16x8 y = *(const bf16x8*)(wr + k2);
            #pragma unroll
            for (int e = 0; e < 8; ++e) s += (float)x[e]*(float)y[e];
          }
          qp[tid] = s;
        }
        __syncthreads();
        if (tid < 128) qv[tid] = qp[tid] + qp[tid+128];
        __syncthreads();
        // energies
        {
          for (int tl = wv; tl < 200; tl += 4){
            const float* pmrow = pm + ((size_t)b*200 + tl)*128;
            float s = 0.f;
            #pragma unroll
            for (int half = 0; half < 2; ++half){
              int a = l + half*64;
              float x = qv[a] + pmrow[a];
              #pragma unroll
              for (int f = 0; f < 32; ++f) x += locb[tl][f]*wlocT[f][a];
              s += vvp[a]*tanhf_(x);
            }
            #pragma unroll
            for (int o = 32; o; o >>= 1) s += __shfl_xor(s, o);
            if (l == 0) es[tl] = s;
          }
        }
        __syncthreads();
        // softmax over 200
        {
          float e0 = (tid < 200) ? es[tid] : -3.0e38f;
          float m = e0;
          #pragma unroll
          for (int o = 32; o; o >>= 1) m = fmaxf(m, __shfl_xor(m, o));
          if (l == 0) sred[wv] = m;
          __syncthreads();
          m = fmaxf(fmaxf(sred[0],sred[1]), fmaxf(sred[2],sred[3]));
          float p = (tid < 200) ? __expf(e0 - m) : 0.f;
          float ss = p;
          #pragma unroll
          for (int o = 32; o; o >>= 1) ss += __shfl_xor(ss, o);
          __syncthreads();
          if (l == 0) sred[wv] = ss;
          __syncthreads();
          ss = sred[0]+sred[1]+sred[2]+sred[3];
          float aval = p / ss;
          if (tid < 200){
            awl[tid] = aval;
            out_attn[((size_t)b*200 + i)*200 + tid] = aval;
          }
        }
        __syncthreads();
        // context = align @ enc  (2 adjacent dims per thread)
        {
          const u32* ep = (const u32*)(enc_bf + (size_t)b*102400) + tid;
          float s0 = 0.f, s1 = 0.f;
          #pragma unroll 4
          for (int t = 0; t < 200; ++t){
            U2h w; w.u = ep[(size_t)t*256];
            float a = awl[t];
            s0 += a*(float)w.h[0];
            s1 += a*(float)w.h[1];
          }
          U2h cb; cb.h[0] = (bf16)s0; cb.h[1] = (bf16)s1;
          stu((u32*)(xa + (size_t)b*1792 + 256)  + tid, cb.u);
          stu((u32*)(xd + (size_t)b*2560 + 1024) + tid, cb.u);
          *((u32*)(proj + ((size_t)i*64 + b)*1536 + 1024) + tid) = cb.u;
        }
      }
    }
    gridbar(cnt, ++nb * NBLK);
  }
}

// ---------------- epilogue scatter -------------------------------------------------
__global__ void scatter_out(const float* __restrict__ mt_, float* __restrict__ out){
  int i = blockIdx.x*256 + threadIdx.x;
  const int NMEL = 12800*160;
  if (i < NMEL){
    int sb = i / 160, j = i % 160;
    int s = sb >> 6, b = sb & 63;
    int r = j / 80, mm = j % 80;
    out[((size_t)b*400 + 2*s + r)*80 + mm] = mt_[(size_t)sb*176 + j];
  } else if (i < NMEL + 12800){
    int sb = i - NMEL;
    int s = sb >> 6, b = sb & 63;
    float st = sigf(mt_[(size_t)sb*176 + 160]);
    float* so = out + 2048000;
    so[(size_t)b*400 + 2*s]     = st;
    so[(size_t)b*400 + 2*s + 1] = st;
  }
}

// ==================================================================================
extern "C" void kernel_launch(void* const* d_in, const int* in_sizes, int n_in,
                              void* d_out, int out_size, void* d_ws, size_t ws_size,
                              hipStream_t stream)
{
  const float* enc   = (const float*)d_in[0];
  const float* inp   = (const float*)d_in[1];
  const float* Wpre1 = (const float*)d_in[2];
  const float* bpre1 = (const float*)d_in[3];
  const float* Wpre2 = (const float*)d_in[4];
  const float* bpre2 = (const float*)d_in[5];
  const float* Wmem  = (const float*)d_in[6];
  const float* Wiha  = (const float*)d_in[7];
  const float* Whha  = (const float*)d_in[8];
  const float* biha  = (const float*)d_in[9];
  const float* bhha  = (const float*)d_in[10];
  const float* Wq    = (const float*)d_in[11];
  const float* Wconv = (const float*)d_in[12];
  const float* Wloc  = (const float*)d_in[13];
  const float* vv    = (const float*)d_in[14];
  const float* Wihd  = (const float*)d_in[15];
  const float* Whhd  = (const float*)d_in[16];
  const float* bihd  = (const float*)d_in[17];
  const float* bhhd  = (const float*)d_in[18];
  const float* Wmel  = (const float*)d_in[19];
  const float* bmel  = (const float*)d_in[20];
  const float* Wstop = (const float*)d_in[21];
  const float* bstop = (const float*)d_in[22];
  float* out = (float*)d_out;

  char* pp = (char*)d_ws;
  auto carve = [&](size_t bytes)->char*{
    char* r = (char*)(((uintptr_t)pp + 255) & ~(uintptr_t)255);
    pp = r + bytes;
    return r;
  };
  bf16*  enc_bf  = (bf16*) carve((size_t)64*200*512*2);
  float* pm      = (float*)carve((size_t)64*200*128*4);
  bf16*  decin   = (bf16*) carve((size_t)12800*96*2);
  bf16*  h1      = (bf16*) carve((size_t)12800*256*2);
  bf16*  pall    = (bf16*) carve((size_t)12800*256*2);
  bf16*  Wp1b    = (bf16*) carve((size_t)256*96*2);
  bf16*  Wp2b    = (bf16*) carve((size_t)256*256*2);
  bf16*  Wmemb   = (bf16*) carve((size_t)128*512*2);
  bf16*  Wqb     = (bf16*) carve((size_t)128*1024*2);
  bf16*  Wca     = (bf16*) carve((size_t)4096*KA*2);
  bf16*  Wcd     = (bf16*) carve((size_t)4096*KD*2);
  bf16*  Wmc     = (bf16*) carve((size_t)176*1536*2);
  float* biasa   = (float*)carve(4096*4);
  float* biasd   = (float*)carve(4096*4);
  float* bias176 = (float*)carve(176*4);
  bf16*  proj    = (bf16*) carve((size_t)12800*1536*2);
  float* meltmp  = (float*)carve((size_t)12800*176*4);
  float* ga      = (float*)carve((size_t)64*4096*4);
  float* gd      = (float*)carve((size_t)64*4096*4);
  // zeroed-every-launch state block (contiguous)
  bf16*  xa  = (bf16*) carve((size_t)64*1792*2);
  bf16*  xd  = (bf16*) carve((size_t)64*2560*2);
  float* ac  = (float*)carve((size_t)64*1024*4);
  float* dc  = (float*)carve((size_t)64*1024*4);
  unsigned* cnt = (unsigned*)carve(256);
  size_t zbytes = (size_t)((char*)cnt + 256 - (char*)xa);
  hipMemsetAsync(xa, 0, zbytes, stream);

  // ---- prologue: conversions / packing ----
  cvt_kernel<<<(6553600+255)/256,256,0,stream>>>(enc,   enc_bf, 6553600);
  cvt_kernel<<<(131072+255)/256, 256,0,stream>>>(Wq,    Wqb,    131072);
  cvt_kernel<<<(65536+255)/256,  256,0,stream>>>(Wmem,  Wmemb,  65536);
  cvt_kernel<<<(65536+255)/256,  256,0,stream>>>(Wpre2, Wp2b,   65536);
  cvt_pad_kernel<<<(256*96+255)/256,256,0,stream>>>(Wpre1, Wp1b, 256, 80, 96);
  cat_cvt_kernel<<<(4096*KA+255)/256,256,0,stream>>>(Wiha, 768,  Whha, 1024, Wca, 4096);
  cat_cvt_kernel<<<(4096*KD+255)/256,256,0,stream>>>(Wihd, 1536, Whhd, 1024, Wcd, 4096);
  build_wmelcat<<<(176*1536+255)/256,256,0,stream>>>(Wmel, Wstop, Wmc);
  build_misc<<<(8368+255)/256,256,0,stream>>>(biha,bhha,biasa, bihd,bhhd,biasd, bmel,bstop,bias176);
  build_decin<<<(12800*96+255)/256,256,0,stream>>>(inp, decin);

  // ---- prologue: batched GEMMs ----
  gemm_k<1,1><<<800,256,0,stream>>>(decin, Wp1b, bpre1, nullptr, h1, 12800,256,96, 200);
  gemm_k<1,1><<<800,256,0,stream>>>(h1, Wp2b, bpre2, nullptr, pall, 12800,256,256, 200);
  gemm_k<0,0><<<400,256,0,stream>>>(enc_bf, Wmemb, nullptr, pm, nullptr, 12800,128,512, 200);

  // ---- the whole 200-step scan as ONE persistent kernel ----
  float* out_attn = out + 2073600;
  decoder_scan<<<NBLK,256,0,stream>>>(pall, Wca, Wcd, biasa, biasd,
                                      Wqb, Wconv, Wloc, vv, pm, enc_bf,
                                      xa, xd, ga, gd, ac, dc,
                                      proj, out_attn, cnt);

  // ---- epilogue: mel/stop projection + scatter ----
  gemm_k<0,0><<<550,256,0,stream>>>(proj, Wmc, bias176, meltmp, nullptr, 12800,176,1536, 200);
  scatter_out<<<(12800*160+12800+255)/256,256,0,stream>>>(meltmp, out);
}